// Round 1
// baseline (217.684 us; speedup 1.0000x reference)
//
#include <hip/hip_runtime.h>

// Problem constants (fixed by setup_inputs)
#define BB 8
#define TC 1024
#define EE 256
#define KJ 8
#define MSEL 2048
#define V1 17          // V+1
#define T1 8192        // TC*KJ
#define TTOT 24576     // T1 + M*K
#define BI_TOT 16384   // BB*MSEL
#define NCOL 136       // KJ*V1
#define NCOLP 144      // KJ*18 (v padded to 18)

// Workspace layout (bytes)
#define SCAL_OFF 0                         // 32 ints: [0]=maxdepth [1..8]=len1 [9..16]=mix1 [17..24]=cnt
#define SEL_OFF  1024                      // 16384 ints
#define GRP_OFF  (SEL_OFF + 65536)         // 8*16384 ints
#define WF_OFF   (GRP_OFF + 524288)        // Wfused [e][j][v]: 256*136 f32
#define B2_OFF   (WF_OFF + 139264)         // bias2 [j][v]: 136 f32
#define BF0_OFF  (B2_OFF + 1024)           // bfused0: 17 f32
#define WC_OFF   (BF0_OFF + 1024)          // Wcomb [g][e][col=j*18+v]: 8*256*144 f32

__global__ __launch_bounds__(256) void k_maxdepth(const int* depth, int* scal) {
    int idx = blockIdx.x * 256 + threadIdx.x;
    int v = depth[idx];
    #pragma unroll
    for (int d = 32; d; d >>= 1) v = max(v, __shfl_down(v, d, 64));
    __shared__ int sm[4];
    int lane = threadIdx.x & 63, wid = threadIdx.x >> 6;
    if (lane == 0) sm[wid] = v;
    __syncthreads();
    if (threadIdx.x == 0) atomicMax(&scal[0], max(max(sm[0], sm[1]), max(sm[2], sm[3])));
}

__global__ __launch_bounds__(256) void k_len1(const int* depth, int* scal) {
    int idx = blockIdx.x * 256 + threadIdx.x;
    int b = idx / TTOT;                    // uniform per block (TTOT % 256 == 0)
    int md = scal[0];
    unsigned long long bal = __ballot(depth[idx] == md - 1);
    __shared__ int sm[4];
    int lane = threadIdx.x & 63, wid = threadIdx.x >> 6;
    if (lane == 0) sm[wid] = __popcll(bal);
    __syncthreads();
    if (threadIdx.x == 0) {
        int t = sm[0] + sm[1] + sm[2] + sm[3];
        if (t) atomicAdd(&scal[1 + b], t);
    }
}

// One block per batch: stable compaction of first MSEL positions with value==2 (t<len1)
__global__ __launch_bounds__(256) void k_scan(const int* value, int* scal, int* sel) {
    int b = blockIdx.x, tid = threadIdx.x;
    int len1 = scal[1 + b];
    const int* vb = value + b * TTOT;
    int t0 = tid * 32;                      // thread owns contiguous [t0, t0+32)
    unsigned mask = 0;
    #pragma unroll
    for (int k = 0; k < 32; k += 4) {
        int4 v = *(const int4*)(vb + t0 + k);
        if (t0 + k + 0 < len1 && v.x == 2) mask |= 1u << (k + 0);
        if (t0 + k + 1 < len1 && v.y == 2) mask |= 1u << (k + 1);
        if (t0 + k + 2 < len1 && v.z == 2) mask |= 1u << (k + 2);
        if (t0 + k + 3 < len1 && v.w == 2) mask |= 1u << (k + 3);
    }
    int cnt = __popc(mask);
    int inc = cnt;
    #pragma unroll
    for (int d = 1; d < 64; d <<= 1) {
        int n = __shfl_up(inc, d, 64);
        if ((tid & 63) >= d) inc += n;
    }
    __shared__ int wt[4];
    int lane = tid & 63, wid = tid >> 6;
    if (lane == 63) wt[wid] = inc;
    __syncthreads();
    int woff = 0;
    for (int w = 0; w < wid; ++w) woff += wt[w];
    int off = woff + inc - cnt;
    #pragma unroll
    for (int k = 0; k < 32; ++k) {
        if (mask & (1u << k)) {
            if (off < MSEL) sel[b * MSEL + off] = t0 + k;
            off++;
        }
    }
    if (tid == 0) scal[9 + b] = wt[0] + wt[1] + wt[2] + wt[3];   // mix_1[b]
}

// Bin (b,i) entries by jsel = sel%8
__global__ __launch_bounds__(256) void k_group(const int* sel, int* scal, int* groups) {
    __shared__ int lcnt[KJ], lbase[KJ];
    if (threadIdx.x < KJ) lcnt[threadIdx.x] = 0;
    __syncthreads();
    int idx = blockIdx.x * 256 + threadIdx.x;          // = b*MSEL + i
    int b = idx >> 11, i = idx & (MSEL - 1);
    int valid = (i < scal[9 + b]) ? 1 : 0;
    int t = valid ? sel[idx] : 0;
    int g = t & 7, tq = t >> 3;
    int lslot = atomicAdd(&lcnt[g], 1);
    __syncthreads();
    if (threadIdx.x < KJ) lbase[threadIdx.x] = atomicAdd(&scal[17 + threadIdx.x], lcnt[threadIdx.x]);
    __syncthreads();
    groups[g * BI_TOT + lbase[g] + lslot] = (idx << 11) | (tq << 1) | valid;
}

// Wfused[e][j][v] = sum_o W0[e,o,j] * Wl[v,o]
__global__ __launch_bounds__(256) void k_wfused(const float* W0, const float* Wl, float* wf) {
    int e = blockIdx.x;
    __shared__ float w0s[EE * KJ];
    __shared__ float wls[V1 * EE];
    for (int idx = threadIdx.x; idx < EE * KJ; idx += 256) w0s[idx] = W0[e * EE * KJ + idx];
    for (int idx = threadIdx.x; idx < V1 * EE; idx += 256) wls[idx] = Wl[idx];
    __syncthreads();
    int tid = threadIdx.x;
    if (tid < NCOL) {
        int j = tid / V1, v = tid - j * V1;
        float acc = 0.f;
        for (int o = 0; o < EE; ++o) acc += w0s[o * KJ + j] * wls[v * EE + o];
        wf[e * NCOL + tid] = acc;
    }
}

// bfused0[v] = b0·Wl[v,:] + bl[v];  bias2[j][v] = sum_e b1[e]*Wfused[e][j][v] + bfused0[v]
__global__ __launch_bounds__(256) void k_bias(const float* b0, const float* bl, const float* b1,
                                              const float* Wl, const float* wf,
                                              float* bias2, float* bf0) {
    int tid = threadIdx.x;
    __shared__ float bf0s[V1];
    if (tid < V1) {
        float a = bl[tid];
        for (int o = 0; o < EE; ++o) a += b0[o] * Wl[tid * EE + o];
        bf0[tid] = a; bf0s[tid] = a;
    }
    __syncthreads();
    if (tid < NCOL) {
        int j = tid / V1, v = tid - j * V1;
        (void)j;
        float a = 0.f;
        for (int e = 0; e < EE; ++e) a += b1[e] * wf[e * NCOL + tid];
        bias2[tid] = a + bf0s[v];
    }
}

// Wcomb[g][e][j*18+v] = sum_em W1[e,em,g] * Wfused[em][j][v]
__global__ __launch_bounds__(256) void k_wcomb(const float* W1, const float* wf, float* wc) {
    int g = blockIdx.x >> 3, j = blockIdx.x & 7;
    __shared__ float wfs[EE * 18];
    for (int idx = threadIdx.x; idx < EE * V1; idx += 256) {
        int em = idx / V1, v = idx - em * V1;
        wfs[em * 18 + v] = wf[em * NCOL + j * V1 + v];
    }
    __syncthreads();
    int e = threadIdx.x;
    float acc[V1];
    #pragma unroll
    for (int v = 0; v < V1; ++v) acc[v] = 0.f;
    const float* w1p = W1 + e * (EE * KJ) + g;
    for (int em = 0; em < EE; ++em) {
        float a = w1p[em * KJ];
        #pragma unroll
        for (int v = 0; v < V1; ++v) acc[v] += a * wfs[em * 18 + v];
    }
    float* outp = wc + (g * EE + e) * NCOLP + j * 18;
    #pragma unroll
    for (int v = 0; v < V1; ++v) outp[v] = acc[v];
    outp[V1] = 0.f;   // pad column
}

// Main grouped GEMM: per block (g, 64-row tile): C[64 x 144] += X[64 x 256] * Wcomb_g[256 x 144]
__global__ __launch_bounds__(256) void k_main(const float* x, const float* wc, const int* scal,
                                              const int* groups, const float* bias2,
                                              const float* bf0, float* out) {
    int g = blockIdx.x >> 8;
    int tile = blockIdx.x & 255;
    int cntg = scal[17 + g];
    if (tile * 64 >= cntg) return;
    int nrows = min(64, cntg - tile * 64);

    __shared__ float xs[64 * 69];            // [row][e] pad 69
    __shared__ float wsm[64 * NCOLP];        // [e][col]
    __shared__ int xoffs[64];
    __shared__ int obase[64];
    __shared__ unsigned char vflag[64];      // 0=no row, 1=invalid (bias only), 2=valid

    int tid = threadIdx.x;
    if (tid < 64) {
        int flag = 0, xo = 0, ob = 0;
        if (tid < nrows) {
            int p = groups[g * BI_TOT + tile * 64 + tid];
            int valid = p & 1;
            int tq = (p >> 1) & 1023;
            int bi = p >> 11;
            int b = bi >> 11;
            xo = (b * TC + tq) * EE;
            ob = bi * NCOL;                  // ((b*16384)+(i*8))*17
            flag = 1 + valid;
        }
        xoffs[tid] = xo; obase[tid] = ob; vflag[tid] = (unsigned char)flag;
    }

    int tx = tid & 15;      // rows tx*4 .. tx*4+3
    int ty = tid >> 4;      // cols ty + 16*c

    float acc[4][9];
    #pragma unroll
    for (int r = 0; r < 4; ++r)
        #pragma unroll
        for (int c = 0; c < 9; ++c) acc[r][c] = 0.f;

    for (int ch = 0; ch < 4; ++ch) {
        __syncthreads();
        {   // stage x chunk [64 rows][64 e] -> xs[row][e]
            int q = tid & 15, r4 = tid >> 4;
            #pragma unroll
            for (int rr = 0; rr < 4; ++rr) {
                int row = r4 + rr * 16;
                float4 v = *(const float4*)(x + xoffs[row] + ch * 64 + q * 4);
                float* d = &xs[row * 69 + q * 4];
                d[0] = v.x; d[1] = v.y; d[2] = v.z; d[3] = v.w;
            }
        }
        {   // stage weight chunk [64 e][144 col]
            const float4* src = (const float4*)(wc + (g * EE + ch * 64) * NCOLP);
            #pragma unroll
            for (int p = 0; p < 9; ++p) {
                int idx = tid + p * 256;
                float4 v = src[idx];
                *(float4*)&wsm[idx * 4] = v;
            }
        }
        __syncthreads();
        #pragma unroll 2
        for (int e = 0; e < 64; ++e) {
            float xv[4];
            #pragma unroll
            for (int r = 0; r < 4; ++r) xv[r] = xs[(tx * 4 + r) * 69 + e];
            #pragma unroll
            for (int c = 0; c < 9; ++c) {
                float wv = wsm[e * NCOLP + ty + 16 * c];
                #pragma unroll
                for (int r = 0; r < 4; ++r) acc[r][c] += xv[r] * wv;
            }
        }
    }

    #pragma unroll
    for (int c = 0; c < 9; ++c) {
        int col = ty + 16 * c;
        int j = col / 18;
        int v = col - j * 18;
        if (v < V1) {
            float bias = bias2[j * V1 + v];
            float b0v = bf0[v];
            #pragma unroll
            for (int r = 0; r < 4; ++r) {
                int row = tx * 4 + r;
                int fl = vflag[row];
                if (fl) out[obase[row] + j * V1 + v] = (fl == 2) ? (acc[r][c] + bias) : b0v;
            }
        }
    }
}

extern "C" void kernel_launch(void* const* d_in, const int* in_sizes, int n_in,
                              void* d_out, int out_size, void* d_ws, size_t ws_size,
                              hipStream_t stream) {
    const float* x     = (const float*)d_in[0];
    const int*   value = (const int*)d_in[1];
    const int*   depth = (const int*)d_in[2];
    // d_in[3] = pos (unused), d_in[4] = num_mix (constant 2048)
    const float* W1    = (const float*)d_in[5];
    const float* b1    = (const float*)d_in[6];
    const float* W0    = (const float*)d_in[7];
    const float* b0    = (const float*)d_in[8];
    const float* Wl    = (const float*)d_in[9];
    const float* bl    = (const float*)d_in[10];
    float* out = (float*)d_out;
    char* ws = (char*)d_ws;

    int*   scal   = (int*)(ws + SCAL_OFF);
    int*   sel    = (int*)(ws + SEL_OFF);
    int*   groups = (int*)(ws + GRP_OFF);
    float* wf     = (float*)(ws + WF_OFF);
    float* bias2  = (float*)(ws + B2_OFF);
    float* bf0    = (float*)(ws + BF0_OFF);
    float* wc     = (float*)(ws + WC_OFF);

    hipMemsetAsync(scal, 0, 128, stream);
    k_maxdepth<<<dim3((BB * TTOT) / 256), dim3(256), 0, stream>>>(depth, scal);
    k_len1    <<<dim3((BB * TTOT) / 256), dim3(256), 0, stream>>>(depth, scal);
    k_scan    <<<dim3(BB),   dim3(256), 0, stream>>>(value, scal, sel);
    k_group   <<<dim3(64),   dim3(256), 0, stream>>>(sel, scal, groups);
    k_wfused  <<<dim3(EE),   dim3(256), 0, stream>>>(W0, Wl, wf);
    k_bias    <<<dim3(1),    dim3(256), 0, stream>>>(b0, bl, b1, Wl, wf, bias2, bf0);
    k_wcomb   <<<dim3(64),   dim3(256), 0, stream>>>(W1, wf, wc);
    k_main    <<<dim3(8 * 256), dim3(256), 0, stream>>>(x, wc, scal, groups, bias2, bf0, out);
}